// Round 1
// baseline (1036.481 us; speedup 1.0000x reference)
//
#include <hip/hip_runtime.h>
#include <math.h>

#define THW 65536
#define HW  4096
#define C96 96
#ifndef M_PI
#define M_PI 3.14159265358979323846
#endif

// ---------------- basis init (once per launch; ws is re-poisoned each call) --
__global__ __launch_bounds__(256) void init_basis_k(float* __restrict__ b64,
                                                    float* __restrict__ b16) {
  int tid = threadIdx.x;
  for (int i = tid; i < 4096; i += 256) {
    int n = i >> 6, x = i & 63;
    double s = sqrt(2.0 / 64.0) * (n == 0 ? sqrt(0.5) : 1.0);
    b64[i] = (float)(cos((double)n * ((double)x + 0.5) * M_PI / 64.0) * s);
  }
  {
    int n = tid >> 4, x = tid & 15;
    double s = sqrt(2.0 / 16.0) * (n == 0 ? sqrt(0.5) : 1.0);
    b16[tid & 255] = (float)(cos((double)n * ((double)x + 0.5) * M_PI / 16.0) * s);
  }
}

// ---------------- depthwise 3x3x3 conv, pad 1 --------------------------------
__global__ __launch_bounds__(256) void dwconv_k(const float* __restrict__ x,
    const float* __restrict__ wv, const float* __restrict__ bias,
    float* __restrict__ y) {
  int tid = threadIdx.x;
  int hw = blockIdx.x * 256 + tid;      // 0..4095
  int t  = blockIdx.y;                  // 0..15
  int bc = blockIdx.z;                  // 0..191
  int c  = bc % C96;
  int h = hw >> 6, w = hw & 63;
  float w27[27];
#pragma unroll
  for (int i = 0; i < 27; ++i) w27[i] = wv[c * 27 + i];
  const float* xp = x + (size_t)bc * THW;
  float acc = bias[c];
#pragma unroll
  for (int dt = -1; dt <= 1; ++dt) {
    int tt = t + dt;
    if (tt < 0 || tt > 15) continue;
#pragma unroll
    for (int dh = -1; dh <= 1; ++dh) {
      int hh = h + dh;
      if (hh < 0 || hh > 63) continue;
#pragma unroll
      for (int dw = -1; dw <= 1; ++dw) {
        int ww = w + dw;
        if (ww < 0 || ww > 63) continue;
        acc += xp[tt * HW + hh * 64 + ww] * w27[(dt + 1) * 9 + (dh + 1) * 3 + (dw + 1)];
      }
    }
  }
  y[(size_t)bc * THW + t * HW + hw] = acc;
}

// ---------------- linear 96 -> 192 (xg | z), channel-first -------------------
__global__ __launch_bounds__(256) void lin_k(const float* __restrict__ in,
    const float* __restrict__ W, const float* __restrict__ bias,
    float* __restrict__ xg, float* __restrict__ z) {
  __shared__ float ws[9216];
  int tid = threadIdx.x;
  int s = blockIdx.x * 256 + tid;
  int b = blockIdx.y;
  const float* ip = in + (size_t)b * C96 * THW + s;
  float iv[96];
#pragma unroll
  for (int ci = 0; ci < 96; ++ci) iv[ci] = ip[ci * THW];
  for (int half = 0; half < 2; ++half) {
    __syncthreads();
    for (int i = tid; i < 9216; i += 256) ws[i] = W[half * 9216 + i];
    __syncthreads();
    float* op = (half == 0 ? xg : z) + (size_t)b * C96 * THW + s;
#pragma unroll 1
    for (int co = 0; co < 96; ++co) {
      float acc = bias[half * 96 + co];
      const float4* wr = (const float4*)&ws[co * 96];
#pragma unroll
      for (int k = 0; k < 24; ++k) {
        float4 w4 = wr[k];
        acc += w4.x * iv[4 * k] + w4.y * iv[4 * k + 1] +
               w4.z * iv[4 * k + 2] + w4.w * iv[4 * k + 3];
      }
      op[co * THW] = acc;
    }
  }
}

// ---------------- generic 96x96 matvec (v0), channel-first -------------------
__global__ __launch_bounds__(256) void gemv96_k(const float* __restrict__ in,
    const float* __restrict__ W, const float* __restrict__ bias,
    float* __restrict__ out) {
  __shared__ float ws[9216];
  int tid = threadIdx.x;
  int s = blockIdx.x * 256 + tid;
  int b = blockIdx.y;
  for (int i = tid; i < 9216; i += 256) ws[i] = W[i];
  const float* ip = in + (size_t)b * C96 * THW + s;
  float iv[96];
#pragma unroll
  for (int ci = 0; ci < 96; ++ci) iv[ci] = ip[ci * THW];
  __syncthreads();
  float* op = out + (size_t)b * C96 * THW + s;
#pragma unroll 1
  for (int co = 0; co < 96; ++co) {
    float acc = bias[co];
    const float4* wr = (const float4*)&ws[co * 96];
#pragma unroll
    for (int k = 0; k < 24; ++k) {
      float4 w4 = wr[k];
      acc += w4.x * iv[4 * k] + w4.y * iv[4 * k + 1] +
             w4.z * iv[4 * k + 2] + w4.w * iv[4 * k + 3];
    }
    op[co * THW] = acc;
  }
}

// ---------------- tau -> spectral coefficient maps A,B [96,THW] --------------
__global__ __launch_bounds__(256) void tau_k(const float* __restrict__ fe,
    const float* __restrict__ tokW, const float* __restrict__ tokB,
    const float* __restrict__ cS, const float* __restrict__ aS,
    float* __restrict__ A, float* __restrict__ Bc) {
  __shared__ float ws[9216];
  int tid = threadIdx.x;
  int s = blockIdx.x * 256 + tid;
  for (int i = tid; i < 9216; i += 256) ws[i] = tokW[i];
  __syncthreads();
  float fv[96];
  const float4* fp = (const float4*)(fe + (size_t)s * 96);
#pragma unroll
  for (int k = 0; k < 24; ++k) {
    float4 v = fp[k];
    fv[4 * k] = v.x; fv[4 * k + 1] = v.y; fv[4 * k + 2] = v.z; fv[4 * k + 3] = v.w;
  }
  float cv = cS[0], al = aS[0];
  float rc = 1.0f / (cv + 1e-8f);
#pragma unroll 1
  for (int co = 0; co < 96; ++co) {
    float acc = tokB[co];
    const float4* wr = (const float4*)&ws[co * 96];
#pragma unroll
    for (int k = 0; k < 24; ++k) {
      float4 w4 = wr[k];
      acc += w4.x * fv[4 * k] + w4.y * fv[4 * k + 1] +
             w4.z * fv[4 * k + 2] + w4.w * fv[4 * k + 3];
    }
    float tau = 0.5f * acc * (1.0f + erff(acc * 0.70710678118654752f)); // exact GELU
    float ct = cv * tau;
    float damp = expf(-0.5f * al * tau);
    float sc, cc;
    sincosf(ct, &sc, &cc);
    A[co * THW + s]  = damp * (cc + sc * al * 0.5f * rc);
    Bc[co * THW + s] = damp * sc * rc;
  }
}

// ---------------- fused W+H (I)DCT on one 64x64 plane ------------------------
// DCT:  Bs[w][n] = Cmat[n][w];  IDCT: Bs[w][n] = Cmat[w][n].
// step1: Y[h][n] = sum_w X[h][w]*Bs[w][n]   (per-lane Bs read, uniform XT b128)
// step2: Z[m][n] = sum_h Y[h][n]*Bs[h][m]   (per-lane Y read, uniform Bs b128)
template <bool DCT>
__global__ __launch_bounds__(256) void wh_k(const float* __restrict__ in,
    float* __restrict__ out, const float* __restrict__ b64) {
  __shared__ float XT[64 * 68];  // XT[w][h]
  __shared__ float Yb[64 * 68];  // Y[h][n]
  __shared__ float Bs[64 * 68];  // Bs[w][n]
  int tid = threadIdx.x;
  const float* ip = in + (size_t)blockIdx.x * HW;
  float* op = out + (size_t)blockIdx.x * HW;
  for (int i = tid; i < 4096; i += 256) {
    int r = i >> 6, cdx = i & 63;
    Bs[r * 68 + cdx] = DCT ? b64[cdx * 64 + r] : b64[r * 64 + cdx];
  }
  for (int i = tid; i < 4096; i += 256) {
    int h = i >> 6, w = i & 63;
    XT[w * 68 + h] = ip[i];
  }
  __syncthreads();
  int n = tid & 63;
  int g = tid >> 6;  // 0..3 -> rows g*16..g*16+15
  {
    float acc[16];
#pragma unroll
    for (int i = 0; i < 16; ++i) acc[i] = 0.0f;
#pragma unroll 4
    for (int w = 0; w < 64; ++w) {
      float bv = Bs[w * 68 + n];
      const float4* xw = (const float4*)&XT[w * 68 + g * 16];
      float4 x0 = xw[0], x1 = xw[1], x2 = xw[2], x3 = xw[3];
      acc[0]  += x0.x * bv; acc[1]  += x0.y * bv; acc[2]  += x0.z * bv; acc[3]  += x0.w * bv;
      acc[4]  += x1.x * bv; acc[5]  += x1.y * bv; acc[6]  += x1.z * bv; acc[7]  += x1.w * bv;
      acc[8]  += x2.x * bv; acc[9]  += x2.y * bv; acc[10] += x2.z * bv; acc[11] += x2.w * bv;
      acc[12] += x3.x * bv; acc[13] += x3.y * bv; acc[14] += x3.z * bv; acc[15] += x3.w * bv;
    }
#pragma unroll
    for (int i = 0; i < 16; ++i) Yb[(g * 16 + i) * 68 + n] = acc[i];
  }
  __syncthreads();
  {
    float acc[16];
#pragma unroll
    for (int i = 0; i < 16; ++i) acc[i] = 0.0f;
#pragma unroll 4
    for (int h = 0; h < 64; ++h) {
      float yv = Yb[h * 68 + n];
      const float4* bw = (const float4*)&Bs[h * 68 + g * 16];
      float4 b0 = bw[0], b1 = bw[1], b2 = bw[2], b3 = bw[3];
      acc[0]  += b0.x * yv; acc[1]  += b0.y * yv; acc[2]  += b0.z * yv; acc[3]  += b0.w * yv;
      acc[4]  += b1.x * yv; acc[5]  += b1.y * yv; acc[6]  += b1.z * yv; acc[7]  += b1.w * yv;
      acc[8]  += b2.x * yv; acc[9]  += b2.y * yv; acc[10] += b2.z * yv; acc[11] += b2.w * yv;
      acc[12] += b3.x * yv; acc[13] += b3.y * yv; acc[14] += b3.z * yv; acc[15] += b3.w * yv;
    }
#pragma unroll
    for (int i = 0; i < 16; ++i) op[(g * 16 + i) * 64 + n] = acc[i];
  }
}

// ---------------- fused T-DCT + spectral multiply + T-IDCT -------------------
__global__ __launch_bounds__(256) void tspec_k(const float* __restrict__ U0,
    const float* __restrict__ V0, const float* __restrict__ A,
    const float* __restrict__ Bc, const float* __restrict__ b16,
    float* __restrict__ out) {
  __shared__ float bs[256];
  int tid = threadIdx.x;
  bs[tid] = b16[tid];
  __syncthreads();
  int hw = blockIdx.x * 256 + tid;
  int c = blockIdx.y, b = blockIdx.z;
  size_t base = ((size_t)(b * C96 + c) * 16) * HW + hw;
  int cbase = c * THW + hw;
  float u[16], v[16];
#pragma unroll
  for (int t = 0; t < 16; ++t) { u[t] = U0[base + t * HW]; v[t] = V0[base + t * HW]; }
  float so[16];
#pragma unroll
  for (int n = 0; n < 16; ++n) {
    float ua = 0.0f, va = 0.0f;
#pragma unroll
    for (int t = 0; t < 16; ++t) { float bb = bs[n * 16 + t]; ua += bb * u[t]; va += bb * v[t]; }
    so[n] = A[cbase + n * HW] * ua + Bc[cbase + n * HW] * va;
  }
#pragma unroll
  for (int t = 0; t < 16; ++t) {
    float acc = 0.0f;
#pragma unroll
    for (int n = 0; n < 16; ++n) acc += so[n] * bs[n * 16 + t];
    out[base + t * HW] = acc;
  }
}

// ---------------- fused LayerNorm + SiLU gate + out linear -------------------
__global__ __launch_bounds__(256) void lnout_k(const float* __restrict__ xf,
    const float* __restrict__ z, const float* __restrict__ lnG,
    const float* __restrict__ lnB, const float* __restrict__ outW,
    const float* __restrict__ outB, float* __restrict__ out) {
  __shared__ float ws[9216];
  __shared__ float lg[96], lb[96], ob[96];
  int tid = threadIdx.x;
  for (int i = tid; i < 9216; i += 256) ws[i] = outW[i];
  if (tid < 96) { lg[tid] = lnG[tid]; lb[tid] = lnB[tid]; ob[tid] = outB[tid]; }
  __syncthreads();
  int s = blockIdx.x * 256 + tid;
  int b = blockIdx.y;
  size_t base = (size_t)b * C96 * THW + s;
  float g[96];
  float sum = 0.0f, sq = 0.0f;
#pragma unroll
  for (int ci = 0; ci < 96; ++ci) {
    float vv = xf[base + ci * THW];
    g[ci] = vv; sum += vv; sq += vv * vv;
  }
  float mu = sum * (1.0f / 96.0f);
  float var = fmaxf(sq * (1.0f / 96.0f) - mu * mu, 0.0f);
  float rstd = 1.0f / sqrtf(var + 1e-5f);
#pragma unroll
  for (int ci = 0; ci < 96; ++ci) {
    float zn = z[base + ci * THW];
    float sig = 1.0f / (1.0f + expf(-zn));
    g[ci] = ((g[ci] - mu) * rstd * lg[ci] + lb[ci]) * (zn * sig);
  }
#pragma unroll 1
  for (int co = 0; co < 96; ++co) {
    float acc = ob[co];
    const float4* wr = (const float4*)&ws[co * 96];
#pragma unroll
    for (int k = 0; k < 24; ++k) {
      float4 w4 = wr[k];
      acc += w4.x * g[4 * k] + w4.y * g[4 * k + 1] +
             w4.z * g[4 * k + 2] + w4.w * g[4 * k + 3];
    }
    out[base + co * THW] = acc;
  }
}

extern "C" void kernel_launch(void* const* d_in, const int* in_sizes, int n_in,
                              void* d_out, int out_size, void* d_ws, size_t ws_size,
                              hipStream_t stream) {
  const float* x    = (const float*)d_in[0];
  const float* fe   = (const float*)d_in[1];
  const float* dww  = (const float*)d_in[2];
  const float* dwb  = (const float*)d_in[3];
  const float* linW = (const float*)d_in[4];
  const float* linB = (const float*)d_in[5];
  const float* v0W  = (const float*)d_in[6];
  const float* v0B  = (const float*)d_in[7];
  const float* tokW = (const float*)d_in[8];
  const float* tokB = (const float*)d_in[9];
  const float* cS   = (const float*)d_in[10];
  const float* aS   = (const float*)d_in[11];
  const float* lnG  = (const float*)d_in[12];
  const float* lnBp = (const float*)d_in[13];
  const float* outW = (const float*)d_in[14];
  const float* outB = (const float*)d_in[15];
  float* out = (float*)d_out;

  float* w = (float*)d_ws;
  const size_t TEN = (size_t)2 * C96 * THW;   // 12,582,912 floats
  float* b64    = w;                 // 4096
  float* b16    = w + 4096;          // 256
  float* buf_y  = w + 8192;          // TEN (reused as DCT scratch / xf)
  float* buf_xg = buf_y + TEN;
  float* buf_z  = buf_xg + TEN;
  float* buf_v0 = buf_z + TEN;
  float* bufA   = buf_v0 + TEN;      // 96*THW
  float* bufB   = bufA + (size_t)C96 * THW;
  size_t need = (size_t)(8192 + 4 * TEN + 2 * (size_t)C96 * THW) * sizeof(float);
  if (ws_size < need) return;  // ~252 MB workspace required

  hipLaunchKernelGGL(init_basis_k, dim3(1), dim3(256), 0, stream, b64, b16);
  hipLaunchKernelGGL(dwconv_k, dim3(16, 16, 192), dim3(256), 0, stream, x, dww, dwb, buf_y);
  hipLaunchKernelGGL(lin_k, dim3(256, 2), dim3(256), 0, stream, buf_y, linW, linB, buf_xg, buf_z);
  hipLaunchKernelGGL(gemv96_k, dim3(256, 2), dim3(256), 0, stream, buf_xg, v0W, v0B, buf_v0);
  hipLaunchKernelGGL(tau_k, dim3(256), dim3(256), 0, stream, fe, tokW, tokB, cS, aS, bufA, bufB);
  // DCT_W,H of xg -> buf_y (y is free after lin_k)
  hipLaunchKernelGGL(wh_k<true>, dim3(3072), dim3(256), 0, stream, buf_xg, buf_y, b64);
  // DCT_W,H of v0 -> buf_xg (xg free after its transform)
  hipLaunchKernelGGL(wh_k<true>, dim3(3072), dim3(256), 0, stream, buf_v0, buf_xg, b64);
  // T-DCT + spectral + T-IDCT -> buf_v0
  hipLaunchKernelGGL(tspec_k, dim3(16, 96, 2), dim3(256), 0, stream, buf_y, buf_xg, bufA, bufB, b16, buf_v0);
  // IDCT_W,H -> buf_y = xf
  hipLaunchKernelGGL(wh_k<false>, dim3(3072), dim3(256), 0, stream, buf_v0, buf_y, b64);
  // LN + gate + out linear -> d_out
  hipLaunchKernelGGL(lnout_k, dim3(256, 2), dim3(256), 0, stream, buf_y, buf_z, lnG, lnBp, outW, outB, out);
}

// Round 2
// 973.295 us; speedup vs baseline: 1.0649x; 1.0649x over previous
//
#include <hip/hip_runtime.h>
#include <math.h>

#define THW 65536
#define HW  4096
#define C96 96
#ifndef M_PI
#define M_PI 3.14159265358979323846
#endif

// ---------------- basis init (once per launch; ws is re-poisoned each call) --
__global__ __launch_bounds__(256) void init_basis_k(float* __restrict__ b64,
                                                    float* __restrict__ b16) {
  int tid = threadIdx.x;
  for (int i = tid; i < 4096; i += 256) {
    int n = i >> 6, x = i & 63;
    double s = sqrt(2.0 / 64.0) * (n == 0 ? sqrt(0.5) : 1.0);
    b64[i] = (float)(cos((double)n * ((double)x + 0.5) * M_PI / 64.0) * s);
  }
  {
    int n = tid >> 4, x = tid & 15;
    double s = sqrt(2.0 / 16.0) * (n == 0 ? sqrt(0.5) : 1.0);
    b16[tid & 255] = (float)(cos((double)n * ((double)x + 0.5) * M_PI / 16.0) * s);
  }
}

// ---------------- depthwise 3x3x3 conv, pad 1 --------------------------------
__global__ __launch_bounds__(256) void dwconv_k(const float* __restrict__ x,
    const float* __restrict__ wv, const float* __restrict__ bias,
    float* __restrict__ y) {
  int tid = threadIdx.x;
  int hw = blockIdx.x * 256 + tid;      // 0..4095
  int t  = blockIdx.y;                  // 0..15
  int bc = blockIdx.z;                  // 0..191
  int c  = bc % C96;
  int h = hw >> 6, w = hw & 63;
  float w27[27];
#pragma unroll
  for (int i = 0; i < 27; ++i) w27[i] = wv[c * 27 + i];
  const float* xp = x + (size_t)bc * THW;
  float acc = bias[c];
#pragma unroll
  for (int dt = -1; dt <= 1; ++dt) {
    int tt = t + dt;
    if (tt < 0 || tt > 15) continue;
#pragma unroll
    for (int dh = -1; dh <= 1; ++dh) {
      int hh = h + dh;
      if (hh < 0 || hh > 63) continue;
#pragma unroll
      for (int dw = -1; dw <= 1; ++dw) {
        int ww = w + dw;
        if (ww < 0 || ww > 63) continue;
        acc += xp[tt * HW + hh * 64 + ww] * w27[(dt + 1) * 9 + (dh + 1) * 3 + (dw + 1)];
      }
    }
  }
  y[(size_t)bc * THW + t * HW + hw] = acc;
}

// ---------------- fe transpose: [THW][96] -> [96][THW] -----------------------
__global__ __launch_bounds__(256) void feT_k(const float* __restrict__ fe,
                                             float* __restrict__ feT) {
  __shared__ float t[96 * 65];
  int tid = threadIdx.x;
  int tok0 = blockIdx.x * 64;
  const float* p = fe + (size_t)tok0 * 96;
  for (int i = tid; i < 6144; i += 256) {
    int tok = i / 96;
    int ch = i - tok * 96;
    t[ch * 65 + tok] = p[i];
  }
  __syncthreads();
  for (int i = tid; i < 6144; i += 256) {
    int ch = i >> 6, tok = i & 63;
    feT[(size_t)ch * THW + tok0 + tok] = t[ch * 65 + tok];
  }
}

// ---------------- register-blocked 96xN GEMM family --------------------------
// Out[co][n] = sum_k W[co][k] * In[k][n]  (+ epilogue)
// EPI 0: + bias, plain store
// EPI 1: tau path: t=acc(+bias preloaded); tau=gelu(t); write A,B maps
// EPI 2: LN+SiLU-gate prologue applied to In elements; bias preloaded = out_b
#define FMA4(A, WV) \
  A.x = fmaf(WV, v.x, A.x); A.y = fmaf(WV, v.y, A.y); \
  A.z = fmaf(WV, v.z, A.z); A.w = fmaf(WV, v.w, A.w);

template <int EPI>
__global__ __launch_bounds__(256, 2) void gemm96_k(
    const float* __restrict__ In, const float* __restrict__ W,
    const float* __restrict__ bias, float* __restrict__ Out,
    float* __restrict__ Out2, const float* __restrict__ zg,
    const float* __restrict__ lnG, const float* __restrict__ lnB,
    const float* __restrict__ scal_c, const float* __restrict__ scal_a,
    int N, size_t inStride, size_t outStride) {
  __shared__ float Wt[9216];  // [k][co]
  int tid = threadIdx.x;
  for (int i = tid; i < 9216; i += 256) {
    int co = i / 96, k = i - co * 96;
    Wt[k * 96 + co] = W[i];
  }
  int out_g = tid >> 6;            // 0..3 -> outputs out_g*24..+23
  int tok_g = tid & 63;
  int n0 = blockIdx.x * 256 + tok_g * 4;
  int co0 = out_g * 24;
  const float* ip = In + blockIdx.y * inStride + n0;
  const float* zp = (EPI == 2) ? (zg + blockIdx.y * inStride + n0) : nullptr;

  float4 mu4, rs4;
  if (EPI == 2) {
    float4 sum = make_float4(0.f, 0.f, 0.f, 0.f);
    float4 sq  = make_float4(0.f, 0.f, 0.f, 0.f);
#pragma unroll 8
    for (int ci = 0; ci < 96; ++ci) {
      float4 t = *(const float4*)(ip + (size_t)ci * N);
      sum.x += t.x; sum.y += t.y; sum.z += t.z; sum.w += t.w;
      sq.x = fmaf(t.x, t.x, sq.x); sq.y = fmaf(t.y, t.y, sq.y);
      sq.z = fmaf(t.z, t.z, sq.z); sq.w = fmaf(t.w, t.w, sq.w);
    }
    const float r96 = 1.0f / 96.0f;
    mu4.x = sum.x * r96; mu4.y = sum.y * r96; mu4.z = sum.z * r96; mu4.w = sum.w * r96;
    rs4.x = rsqrtf(fmaxf(sq.x * r96 - mu4.x * mu4.x, 0.f) + 1e-5f);
    rs4.y = rsqrtf(fmaxf(sq.y * r96 - mu4.y * mu4.y, 0.f) + 1e-5f);
    rs4.z = rsqrtf(fmaxf(sq.z * r96 - mu4.z * mu4.z, 0.f) + 1e-5f);
    rs4.w = rsqrtf(fmaxf(sq.w * r96 - mu4.w * mu4.w, 0.f) + 1e-5f);
  }

  float4 acc[24];
#pragma unroll
  for (int j = 0; j < 24; ++j) {
    float bj = bias[co0 + j];
    acc[j] = make_float4(bj, bj, bj, bj);
  }
  __syncthreads();

#pragma unroll 4
  for (int k = 0; k < 96; ++k) {
    float4 v = *(const float4*)(ip + (size_t)k * N);
    if (EPI == 2) {
      float4 zz = *(const float4*)(zp + (size_t)k * N);
      float lgk = lnG[k], lbk = lnB[k];
      float gx = zz.x * __builtin_amdgcn_rcpf(1.0f + __expf(-zz.x));
      float gy = zz.y * __builtin_amdgcn_rcpf(1.0f + __expf(-zz.y));
      float gz = zz.z * __builtin_amdgcn_rcpf(1.0f + __expf(-zz.z));
      float gw = zz.w * __builtin_amdgcn_rcpf(1.0f + __expf(-zz.w));
      v.x = fmaf((v.x - mu4.x) * rs4.x, lgk, lbk) * gx;
      v.y = fmaf((v.y - mu4.y) * rs4.y, lgk, lbk) * gy;
      v.z = fmaf((v.z - mu4.z) * rs4.z, lgk, lbk) * gz;
      v.w = fmaf((v.w - mu4.w) * rs4.w, lgk, lbk) * gw;
    }
    const float4* wr = (const float4*)&Wt[k * 96 + co0];
#pragma unroll
    for (int j = 0; j < 6; ++j) {
      float4 wv = wr[j];
      FMA4(acc[4 * j + 0], wv.x);
      FMA4(acc[4 * j + 1], wv.y);
      FMA4(acc[4 * j + 2], wv.z);
      FMA4(acc[4 * j + 3], wv.w);
    }
  }

  if (EPI == 1) {
    float cv = scal_c[0], al = scal_a[0];
    float rc = 1.0f / (cv + 1e-8f);
#pragma unroll 4
    for (int j = 0; j < 24; ++j) {
      float4 a4, b4;
      float t, tau, ct, damp, sc, cc;
      t = acc[j].x; tau = 0.5f * t * (1.0f + erff(t * 0.70710678118654752f));
      ct = cv * tau; damp = expf(-0.5f * al * tau); sincosf(ct, &sc, &cc);
      a4.x = damp * (cc + sc * al * 0.5f * rc); b4.x = damp * sc * rc;
      t = acc[j].y; tau = 0.5f * t * (1.0f + erff(t * 0.70710678118654752f));
      ct = cv * tau; damp = expf(-0.5f * al * tau); sincosf(ct, &sc, &cc);
      a4.y = damp * (cc + sc * al * 0.5f * rc); b4.y = damp * sc * rc;
      t = acc[j].z; tau = 0.5f * t * (1.0f + erff(t * 0.70710678118654752f));
      ct = cv * tau; damp = expf(-0.5f * al * tau); sincosf(ct, &sc, &cc);
      a4.z = damp * (cc + sc * al * 0.5f * rc); b4.z = damp * sc * rc;
      t = acc[j].w; tau = 0.5f * t * (1.0f + erff(t * 0.70710678118654752f));
      ct = cv * tau; damp = expf(-0.5f * al * tau); sincosf(ct, &sc, &cc);
      a4.w = damp * (cc + sc * al * 0.5f * rc); b4.w = damp * sc * rc;
      *(float4*)(Out  + (size_t)(co0 + j) * N + n0) = a4;
      *(float4*)(Out2 + (size_t)(co0 + j) * N + n0) = b4;
    }
  } else {
    float* op = Out + blockIdx.y * outStride + n0;
#pragma unroll
    for (int j = 0; j < 24; ++j)
      *(float4*)(op + (size_t)(co0 + j) * N) = acc[j];
  }
}

// ---------------- fused W+H (I)DCT on one 64x64 plane ------------------------
template <bool DCT>
__global__ __launch_bounds__(256) void wh_k(const float* __restrict__ in,
    float* __restrict__ out, const float* __restrict__ b64) {
  __shared__ float XT[64 * 68];  // XT[w][h]
  __shared__ float Yb[64 * 68];  // Y[h][n]
  __shared__ float Bs[64 * 68];  // Bs[w][n]
  int tid = threadIdx.x;
  const float* ip = in + (size_t)blockIdx.x * HW;
  float* op = out + (size_t)blockIdx.x * HW;
  for (int i = tid; i < 4096; i += 256) {
    int r = i >> 6, cdx = i & 63;
    Bs[r * 68 + cdx] = DCT ? b64[cdx * 64 + r] : b64[r * 64 + cdx];
  }
  for (int i = tid; i < 4096; i += 256) {
    int h = i >> 6, w = i & 63;
    XT[w * 68 + h] = ip[i];
  }
  __syncthreads();
  int n = tid & 63;
  int g = tid >> 6;
  {
    float acc[16];
#pragma unroll
    for (int i = 0; i < 16; ++i) acc[i] = 0.0f;
#pragma unroll 4
    for (int w = 0; w < 64; ++w) {
      float bv = Bs[w * 68 + n];
      const float4* xw = (const float4*)&XT[w * 68 + g * 16];
      float4 x0 = xw[0], x1 = xw[1], x2 = xw[2], x3 = xw[3];
      acc[0]  += x0.x * bv; acc[1]  += x0.y * bv; acc[2]  += x0.z * bv; acc[3]  += x0.w * bv;
      acc[4]  += x1.x * bv; acc[5]  += x1.y * bv; acc[6]  += x1.z * bv; acc[7]  += x1.w * bv;
      acc[8]  += x2.x * bv; acc[9]  += x2.y * bv; acc[10] += x2.z * bv; acc[11] += x2.w * bv;
      acc[12] += x3.x * bv; acc[13] += x3.y * bv; acc[14] += x3.z * bv; acc[15] += x3.w * bv;
    }
#pragma unroll
    for (int i = 0; i < 16; ++i) Yb[(g * 16 + i) * 68 + n] = acc[i];
  }
  __syncthreads();
  {
    float acc[16];
#pragma unroll
    for (int i = 0; i < 16; ++i) acc[i] = 0.0f;
#pragma unroll 4
    for (int h = 0; h < 64; ++h) {
      float yv = Yb[h * 68 + n];
      const float4* bw = (const float4*)&Bs[h * 68 + g * 16];
      float4 b0 = bw[0], b1 = bw[1], b2 = bw[2], b3 = bw[3];
      acc[0]  += b0.x * yv; acc[1]  += b0.y * yv; acc[2]  += b0.z * yv; acc[3]  += b0.w * yv;
      acc[4]  += b1.x * yv; acc[5]  += b1.y * yv; acc[6]  += b1.z * yv; acc[7]  += b1.w * yv;
      acc[8]  += b2.x * yv; acc[9]  += b2.y * yv; acc[10] += b2.z * yv; acc[11] += b2.w * yv;
      acc[12] += b3.x * yv; acc[13] += b3.y * yv; acc[14] += b3.z * yv; acc[15] += b3.w * yv;
    }
#pragma unroll
    for (int i = 0; i < 16; ++i) op[(g * 16 + i) * 64 + n] = acc[i];
  }
}

// ---------------- fused T-DCT + spectral multiply + T-IDCT -------------------
__global__ __launch_bounds__(256) void tspec_k(const float* __restrict__ U0,
    const float* __restrict__ V0, const float* __restrict__ A,
    const float* __restrict__ Bc, const float* __restrict__ b16,
    float* __restrict__ out) {
  __shared__ float bs[256];
  int tid = threadIdx.x;
  bs[tid] = b16[tid];
  __syncthreads();
  int hw = blockIdx.x * 256 + tid;
  int c = blockIdx.y, b = blockIdx.z;
  size_t base = ((size_t)(b * C96 + c) * 16) * HW + hw;
  int cbase = c * THW + hw;
  float u[16], v[16];
#pragma unroll
  for (int t = 0; t < 16; ++t) { u[t] = U0[base + t * HW]; v[t] = V0[base + t * HW]; }
  float so[16];
#pragma unroll
  for (int n = 0; n < 16; ++n) {
    float ua = 0.0f, va = 0.0f;
#pragma unroll
    for (int t = 0; t < 16; ++t) { float bb = bs[n * 16 + t]; ua += bb * u[t]; va += bb * v[t]; }
    so[n] = A[cbase + n * HW] * ua + Bc[cbase + n * HW] * va;
  }
#pragma unroll
  for (int t = 0; t < 16; ++t) {
    float acc = 0.0f;
#pragma unroll
    for (int n = 0; n < 16; ++n) acc += so[n] * bs[n * 16 + t];
    out[base + t * HW] = acc;
  }
}

extern "C" void kernel_launch(void* const* d_in, const int* in_sizes, int n_in,
                              void* d_out, int out_size, void* d_ws, size_t ws_size,
                              hipStream_t stream) {
  const float* x    = (const float*)d_in[0];
  const float* fe   = (const float*)d_in[1];
  const float* dww  = (const float*)d_in[2];
  const float* dwb  = (const float*)d_in[3];
  const float* linW = (const float*)d_in[4];
  const float* linB = (const float*)d_in[5];
  const float* v0W  = (const float*)d_in[6];
  const float* v0B  = (const float*)d_in[7];
  const float* tokW = (const float*)d_in[8];
  const float* tokB = (const float*)d_in[9];
  const float* cS   = (const float*)d_in[10];
  const float* aS   = (const float*)d_in[11];
  const float* lnG  = (const float*)d_in[12];
  const float* lnBp = (const float*)d_in[13];
  const float* outW = (const float*)d_in[14];
  const float* outB = (const float*)d_in[15];
  float* out = (float*)d_out;

  float* w = (float*)d_ws;
  const size_t TEN = (size_t)2 * C96 * THW;   // 12,582,912 floats
  const size_t BST = (size_t)C96 * THW;       // batch stride (floats)
  float* b64    = w;                 // 4096
  float* b16    = w + 4096;          // 256
  float* buf_y  = w + 8192;          // TEN (reused as DCT scratch / xf)
  float* buf_xg = buf_y + TEN;
  float* buf_z  = buf_xg + TEN;
  float* buf_v0 = buf_z + TEN;
  float* bufA   = buf_v0 + TEN;      // 96*THW
  float* bufB   = bufA + BST;
  size_t need = (size_t)(8192 + 4 * TEN + 2 * BST) * sizeof(float);
  if (ws_size < need) return;  // ~252 MB workspace required

  hipLaunchKernelGGL(init_basis_k, dim3(1), dim3(256), 0, stream, b64, b16);
  hipLaunchKernelGGL(dwconv_k, dim3(16, 16, 192), dim3(256), 0, stream, x, dww, dwb, buf_y);
  // lin: y -> xg (rows 0..95) and z (rows 96..191)
  hipLaunchKernelGGL(gemm96_k<0>, dim3(256, 2), dim3(256), 0, stream,
                     buf_y, linW, linB, buf_xg, (float*)nullptr, (const float*)nullptr,
                     (const float*)nullptr, (const float*)nullptr,
                     (const float*)nullptr, (const float*)nullptr, THW, BST, BST);
  hipLaunchKernelGGL(gemm96_k<0>, dim3(256, 2), dim3(256), 0, stream,
                     buf_y, linW + 9216, linB + 96, buf_z, (float*)nullptr, (const float*)nullptr,
                     (const float*)nullptr, (const float*)nullptr,
                     (const float*)nullptr, (const float*)nullptr, THW, BST, BST);
  // fe transpose into buf_v0 (scratch), then tau GEMM -> A,B
  hipLaunchKernelGGL(feT_k, dim3(1024), dim3(256), 0, stream, fe, buf_v0);
  hipLaunchKernelGGL(gemm96_k<1>, dim3(256, 1), dim3(256), 0, stream,
                     buf_v0, tokW, tokB, bufA, bufB, (const float*)nullptr,
                     (const float*)nullptr, (const float*)nullptr,
                     cS, aS, THW, (size_t)0, (size_t)0);
  // v0 = xg @ v0W^T -> buf_v0
  hipLaunchKernelGGL(gemm96_k<0>, dim3(256, 2), dim3(256), 0, stream,
                     buf_xg, v0W, v0B, buf_v0, (float*)nullptr, (const float*)nullptr,
                     (const float*)nullptr, (const float*)nullptr,
                     (const float*)nullptr, (const float*)nullptr, THW, BST, BST);
  // DCT_W,H of xg -> buf_y ; of v0 -> buf_xg
  hipLaunchKernelGGL(wh_k<true>, dim3(3072), dim3(256), 0, stream, buf_xg, buf_y, b64);
  hipLaunchKernelGGL(wh_k<true>, dim3(3072), dim3(256), 0, stream, buf_v0, buf_xg, b64);
  // T-DCT + spectral + T-IDCT -> buf_v0
  hipLaunchKernelGGL(tspec_k, dim3(16, 96, 2), dim3(256), 0, stream, buf_y, buf_xg, bufA, bufB, b16, buf_v0);
  // IDCT_W,H -> buf_y = xf
  hipLaunchKernelGGL(wh_k<false>, dim3(3072), dim3(256), 0, stream, buf_v0, buf_y, b64);
  // LN + gate + out linear -> d_out
  hipLaunchKernelGGL(gemm96_k<2>, dim3(256, 2), dim3(256), 0, stream,
                     buf_y, outW, outB, out, (float*)nullptr, buf_z,
                     lnG, lnBp, (const float*)nullptr, (const float*)nullptr, THW, BST, BST);
}